// Round 2
// baseline (803.664 us; speedup 1.0000x reference)
//
#include <hip/hip_runtime.h>

#define NN 100000   // nodes
#define NE 3200000  // edges
#define NF 512      // in features
#define NH 16       // hidden
#define NC 7        // classes
#define NB ((NN + 255) / 256)   // 391 scan blocks

// ---------------------------------------------------------------------------
// Packed butterfly reduction: acc[16] per lane -> full-wave sum of col j held
// by every lane with (lane&15)==j.  17 shuffles instead of 96.
// ---------------------------------------------------------------------------
__device__ __forceinline__ float reduce16(const float acc[16], int lane) {
  float w8[8];
#pragma unroll
  for (int i = 0; i < 8; ++i) {
    float sel = (lane & 1) ? acc[2 * i + 1] : acc[2 * i];
    float oth = (lane & 1) ? acc[2 * i]     : acc[2 * i + 1];
    w8[i] = sel + __shfl_xor(oth, 1);
  }
  float w4[4];
#pragma unroll
  for (int i = 0; i < 4; ++i) {
    float sel = (lane & 2) ? w8[2 * i + 1] : w8[2 * i];
    float oth = (lane & 2) ? w8[2 * i]     : w8[2 * i + 1];
    w4[i] = sel + __shfl_xor(oth, 2);
  }
  float w2[2];
#pragma unroll
  for (int i = 0; i < 2; ++i) {
    float sel = (lane & 4) ? w4[2 * i + 1] : w4[2 * i];
    float oth = (lane & 4) ? w4[2 * i]     : w4[2 * i + 1];
    w2[i] = sel + __shfl_xor(oth, 4);
  }
  float sel = (lane & 8) ? w2[1] : w2[0];
  float oth = (lane & 8) ? w2[0] : w2[1];
  float v = sel + __shfl_xor(oth, 8);
  v += __shfl_xor(v, 16);
  v += __shfl_xor(v, 32);
  return v;  // every lane: full sum of column (lane&15)
}

// ---------------------------------------------------------------------------
// GEMM1: h0 = x @ W1.  One wave per 2 rows (ILP), W1 in 128 VGPRs/lane.
// ---------------------------------------------------------------------------
__global__ __launch_bounds__(256) void gemm1_kernel(const float* __restrict__ x,
                                                    const float* __restrict__ W1,
                                                    float* __restrict__ h0) {
  const int lane = threadIdx.x & 63;
  const int wave = (blockIdx.x * blockDim.x + threadIdx.x) >> 6;
  const int nw   = (gridDim.x * blockDim.x) >> 6;

  float w[8][NH];
#pragma unroll
  for (int i = 0; i < 4; ++i)
#pragma unroll
    for (int j = 0; j < NH; ++j) {
      w[i][j]     = W1[(4 * lane + i) * NH + j];
      w[4 + i][j] = W1[(256 + 4 * lane + i) * NH + j];
    }

  for (int pr = wave; pr < NN / 2; pr += nw) {
    int r0 = 2 * pr;
    const float4* x0 = (const float4*)(x + (size_t)r0 * NF);
    const float4* x1 = (const float4*)(x + (size_t)(r0 + 1) * NF);
    float4 a0 = x0[lane], b0 = x0[64 + lane];
    float4 a1 = x1[lane], b1 = x1[64 + lane];
    float A0[8] = {a0.x, a0.y, a0.z, a0.w, b0.x, b0.y, b0.z, b0.w};
    float A1[8] = {a1.x, a1.y, a1.z, a1.w, b1.x, b1.y, b1.z, b1.w};
    float c0[NH], c1[NH];
#pragma unroll
    for (int j = 0; j < NH; ++j) { c0[j] = 0.f; c1[j] = 0.f; }
#pragma unroll
    for (int i = 0; i < 8; ++i)
#pragma unroll
      for (int j = 0; j < NH; ++j) {
        c0[j] += A0[i] * w[i][j];
        c1[j] += A1[i] * w[i][j];
      }
    float v0 = reduce16(c0, lane);
    float v1 = reduce16(c1, lane);
    if (lane < 16)      h0[(size_t)r0 * NH + lane] = v0;
    else if (lane < 32) h0[(size_t)(r0 + 1) * NH + (lane & 15)] = v1;
  }
}

// ---------------------------------------------------------------------------
// CSR build: histogram -> 3-phase exclusive scan -> permute
// ---------------------------------------------------------------------------
__global__ __launch_bounds__(256) void hist_kernel(const int* __restrict__ ei,
                                                   int* __restrict__ degcur) {
  int e = blockIdx.x * blockDim.x + threadIdx.x;
  if (e < NE) atomicAdd(&degcur[ei[NE + e]], 1);
}

__global__ __launch_bounds__(256) void bsum_kernel(const int* __restrict__ deg,
                                                   int* __restrict__ bsum) {
  int i = blockIdx.x * blockDim.x + threadIdx.x;
  int lane = threadIdx.x & 63, wid = threadIdx.x >> 6;
  int v = (i < NN) ? deg[i] : 0;
#pragma unroll
  for (int m = 1; m < 64; m <<= 1) v += __shfl_xor(v, m);
  __shared__ int ws[4];
  if (lane == 0) ws[wid] = v;
  __syncthreads();
  if (threadIdx.x == 0) bsum[blockIdx.x] = ws[0] + ws[1] + ws[2] + ws[3];
}

__global__ __launch_bounds__(512) void bscan_kernel(const int* __restrict__ bsum,
                                                    int* __restrict__ boff) {
  __shared__ int tmp[512];
  int tid = threadIdx.x;
  int v = (tid < NB) ? bsum[tid] : 0;
  tmp[tid] = v;
  __syncthreads();
  for (int off = 1; off < 512; off <<= 1) {
    int t = (tid >= off) ? tmp[tid - off] : 0;
    __syncthreads();
    tmp[tid] += t;
    __syncthreads();
  }
  boff[tid] = tmp[tid] - v;  // exclusive
}

__global__ __launch_bounds__(256) void scan_final_kernel(int* __restrict__ degcur,
                                                         const int* __restrict__ boff,
                                                         int* __restrict__ rowstart) {
  int i = blockIdx.x * blockDim.x + threadIdx.x;
  int lane = threadIdx.x & 63, wid = threadIdx.x >> 6;
  int v = (i < NN) ? degcur[i] : 0;
  int sv = v;
#pragma unroll
  for (int d = 1; d < 64; d <<= 1) {
    int t = __shfl_up(sv, d);
    if (lane >= d) sv += t;
  }
  __shared__ int wsum[4];
  if (lane == 63) wsum[wid] = sv;
  __syncthreads();
  int woff = 0;
  for (int w = 0; w < wid; ++w) woff += wsum[w];
  int excl = sv - v + woff + boff[blockIdx.x];
  if (i < NN) {
    rowstart[i] = excl;
    degcur[i]   = excl;   // cursor for permute
    if (i == NN - 1) rowstart[NN] = excl + v;
  }
}

__global__ __launch_bounds__(256) void permute_kernel(const int* __restrict__ ei,
                                                      int* __restrict__ cursor,
                                                      int* __restrict__ ssrc) {
  int e = blockIdx.x * blockDim.x + threadIdx.x;
  if (e >= NE) return;
  int s = ei[e], d = ei[NE + e];
  int pos = atomicAdd(&cursor[d], 1);
  ssrc[pos] = s;
}

// ---------------------------------------------------------------------------
// Layer-1 aggregate (gather): one wave per dst node; 4 lanes/edge (float4),
// 16 edges per iteration.
// ---------------------------------------------------------------------------
__global__ __launch_bounds__(256) void agg1_kernel(const int* __restrict__ rowstart,
                                                   const int* __restrict__ ssrc,
                                                   const float* __restrict__ h0,
                                                   float* __restrict__ agg1) {
  int n = (blockIdx.x * blockDim.x + threadIdx.x) >> 6;
  if (n >= NN) return;
  int lane = threadIdx.x & 63;
  int eg = lane >> 2, c = lane & 3;
  int start = rowstart[n], end = rowstart[n + 1];
  float4 acc = {0.f, 0.f, 0.f, 0.f};
  for (int e = start + eg; e < end; e += 16) {
    int s = ssrc[e];
    float4 hv = *(const float4*)(h0 + (size_t)s * NH + 4 * c);
    acc.x += hv.x; acc.y += hv.y; acc.z += hv.z; acc.w += hv.w;
  }
#pragma unroll
  for (int m = 4; m < 64; m <<= 1) {
    acc.x += __shfl_xor(acc.x, m);
    acc.y += __shfl_xor(acc.y, m);
    acc.z += __shfl_xor(acc.z, m);
    acc.w += __shfl_xor(acc.w, m);
  }
  if (lane < 4) *(float4*)(agg1 + (size_t)n * NH + 4 * lane) = acc;
}

// ---------------------------------------------------------------------------
// Per-node transform: p[n,0:7] = relu(agg1[n]+b1) @ W2, stride 8, p[n,7]=0.
// ---------------------------------------------------------------------------
__global__ __launch_bounds__(256) void transform_kernel(const float* __restrict__ agg1,
                                                        const float* __restrict__ b1,
                                                        const float* __restrict__ W2,
                                                        float* __restrict__ p) {
  int n = blockIdx.x * blockDim.x + threadIdx.x;
  if (n >= NN) return;
  const float4* r = (const float4*)(agg1 + (size_t)n * NH);
  float4 v0 = r[0], v1 = r[1], v2 = r[2], v3 = r[3];
  float h[NH] = {v0.x, v0.y, v0.z, v0.w, v1.x, v1.y, v1.z, v1.w,
                 v2.x, v2.y, v2.z, v2.w, v3.x, v3.y, v3.z, v3.w};
#pragma unroll
  for (int k = 0; k < NH; ++k) h[k] = fmaxf(h[k] + b1[k], 0.f);
#pragma unroll
  for (int j = 0; j < NC; ++j) {
    float acc = 0.f;
#pragma unroll
    for (int k = 0; k < NH; ++k) acc += h[k] * W2[k * NC + j];
    p[(size_t)n * 8 + j] = acc;
  }
  p[(size_t)n * 8 + 7] = 0.f;
}

// ---------------------------------------------------------------------------
// Layer-2 aggregate + bias + log_softmax fused: one wave per dst node;
// 8 lanes/edge (lane&7 = class, class 7 is the zero pad), 8 edges/iter.
// ---------------------------------------------------------------------------
__global__ __launch_bounds__(256) void agg2_lsm_kernel(const int* __restrict__ rowstart,
                                                       const int* __restrict__ ssrc,
                                                       const float* __restrict__ p,
                                                       const float* __restrict__ b2,
                                                       float* __restrict__ out) {
  int n = (blockIdx.x * blockDim.x + threadIdx.x) >> 6;
  if (n >= NN) return;
  int lane = threadIdx.x & 63;
  int eg = lane >> 3, j = lane & 7;
  int start = rowstart[n], end = rowstart[n + 1];
  float acc = 0.f;
  for (int e = start + eg; e < end; e += 8) {
    int s = ssrc[e];
    acc += p[(size_t)s * 8 + j];
  }
#pragma unroll
  for (int m = 8; m < 64; m <<= 1) acc += __shfl_xor(acc, m);
  // lanes 0..7 of each 8-group now hold class sums (j=7 is the pad = 0)
  float z = (j < NC) ? acc + b2[j] : -1e30f;
  float mx = z;
#pragma unroll
  for (int m = 1; m < 8; m <<= 1) mx = fmaxf(mx, __shfl_xor(mx, m));
  float ex = __expf(z - mx);
  float s = ex;
#pragma unroll
  for (int m = 1; m < 8; m <<= 1) s += __shfl_xor(s, m);
  if (j < NC) out[(size_t)n * NC + j] = z - mx - __logf(s);
}

extern "C" void kernel_launch(void* const* d_in, const int* in_sizes, int n_in,
                              void* d_out, int out_size, void* d_ws, size_t ws_size,
                              hipStream_t stream) {
  const float* x  = (const float*)d_in[0];
  const int*   ei = (const int*)d_in[1];
  const float* W1 = (const float*)d_in[2];
  const float* b1 = (const float*)d_in[3];
  const float* W2 = (const float*)d_in[4];
  const float* b2 = (const float*)d_in[5];
  float* out = (float*)d_out;

  // ws layout (~26.4 MB)
  float* h0      = (float*)d_ws;            // NN*16  (later reused as p, stride 8)
  float* agg1    = h0 + (size_t)NN * NH;    // NN*16
  int*   rowstart= (int*)(agg1 + (size_t)NN * NH);  // NN+1
  int*   degcur  = rowstart + NN + 1;       // NN (deg -> cursor)
  int*   bsum    = degcur + NN;             // 512
  int*   boff    = bsum + 512;              // 512
  int*   ssrc    = boff + 512;              // NE
  float* p       = h0;                      // alias: h0 dead after agg1

  const int EB = (NE + 255) / 256;          // 12500

  hipMemsetAsync(degcur, 0, (size_t)NN * sizeof(int), stream);
  hist_kernel<<<EB, 256, 0, stream>>>(ei, degcur);
  bsum_kernel<<<NB, 256, 0, stream>>>(degcur, bsum);
  bscan_kernel<<<1, 512, 0, stream>>>(bsum, boff);
  scan_final_kernel<<<NB, 256, 0, stream>>>(degcur, boff, rowstart);
  permute_kernel<<<EB, 256, 0, stream>>>(ei, degcur, ssrc);

  gemm1_kernel<<<2048, 256, 0, stream>>>(x, W1, h0);
  agg1_kernel<<<(NN * 64 + 255) / 256, 256, 0, stream>>>(rowstart, ssrc, h0, agg1);
  transform_kernel<<<(NN + 255) / 256, 256, 0, stream>>>(agg1, b1, W2, p);
  agg2_lsm_kernel<<<(NN * 64 + 255) / 256, 256, 0, stream>>>(rowstart, ssrc, p, b2, out);
}